// Round 1
// baseline (177.515 us; speedup 1.0000x reference)
//
#include <hip/hip_runtime.h>
#include <hip/hip_bf16.h>
#include <math.h>

typedef __attribute__((ext_vector_type(8))) short short8;
typedef __attribute__((ext_vector_type(4))) float floatx4;

#define MARGIN_C   0.09f
#define SCALE_POS_C 2.0f
#define SCALE_NEG_C 40.0f
#define EPS_C      1e-5f
#define THRESH1_C  0.501f
#define THRESH2_C  0.531f

__device__ __forceinline__ unsigned short f2bf(float f) {
    unsigned u = __float_as_uint(f);
    u += 0x7fffu + ((u >> 16) & 1u);
    return (unsigned short)(u >> 16);
}

__device__ __forceinline__ void gld16(const void* g, void* l) {
    __builtin_amdgcn_global_load_lds(
        (const __attribute__((address_space(1))) void*)g,
        (__attribute__((address_space(3))) void*)l, 16, 0, 0);
}

// ---------------- fp32 -> bf16 conversion (also zeroes the output scalar) ----
__global__ __launch_bounds__(256) void cvt_bf16(const float* __restrict__ in,
                                                unsigned short* __restrict__ out,
                                                float* __restrict__ loss_out,
                                                int n4) {
    int i = blockIdx.x * 256 + threadIdx.x;
    if (i == 0) loss_out[0] = 0.0f;   // harness poisons d_out; we accumulate via atomics
    if (i >= n4) return;
    float4 v = ((const float4*)in)[i];
    ushort4 o;
    o.x = f2bf(v.x); o.y = f2bf(v.y); o.z = f2bf(v.z); o.w = f2bf(v.w);
    ((ushort4*)out)[i] = o;
}

// ---------------- sim = F * F^T, bf16 in / fp32 acc / bf16 out ---------------
// 128x128 block tile, BK=32, 4 waves in 2x2, each wave 64x64 via 4x4 MFMA 16x16x32.
__global__ __launch_bounds__(256) void gemm_sim(const unsigned short* __restrict__ fb,
                                                unsigned short* __restrict__ sim,
                                                int Bn, int Dn) {
    __shared__ __align__(16) unsigned short As[4096]; // 128 rows x 32 k, row-major
    __shared__ __align__(16) unsigned short Bs[4096];

    const int t    = threadIdx.x;
    const int wave = t >> 6;
    const int lane = t & 63;
    const int wr   = wave >> 1, wc = wave & 1;
    const int quad = lane >> 4, m16 = lane & 15;

    // staging: thread t loads 16B (8 bf16): row = t/4 (+64 for chunk1), kk = (t%4)*8
    const int lr = t >> 2;
    const int lk = (t & 3) * 8;
    const unsigned short* gA0 = fb + (size_t)(blockIdx.y * 128 + lr) * Dn + lk;
    const unsigned short* gB0 = fb + (size_t)(blockIdx.x * 128 + lr) * Dn + lk;
    const unsigned short* gA1 = gA0 + (size_t)64 * Dn;
    const unsigned short* gB1 = gB0 + (size_t)64 * Dn;
    unsigned short* lA0 = As + t * 8;          // LDS contiguous: == row-major [128][32]
    unsigned short* lA1 = As + 2048 + t * 8;
    unsigned short* lB0 = Bs + t * 8;
    unsigned short* lB1 = Bs + 2048 + t * 8;

    floatx4 acc[4][4];
#pragma unroll
    for (int i = 0; i < 4; i++)
#pragma unroll
        for (int j = 0; j < 4; j++) acc[i][j] = (floatx4){0.f, 0.f, 0.f, 0.f};

    // fragment read bases: A row = wr*64 + i*16 + m16, k = quad*8
    const unsigned short* pa = As + (wr * 64 + m16) * 32 + quad * 8;
    const unsigned short* pb = Bs + (wc * 64 + m16) * 32 + quad * 8;

    for (int k0 = 0; k0 < Dn; k0 += 32) {
        gld16(gA0 + k0, lA0);
        gld16(gA1 + k0, lA1);
        gld16(gB0 + k0, lB0);
        gld16(gB1 + k0, lB1);
        __syncthreads();
        short8 af[4], bfr[4];
#pragma unroll
        for (int i = 0; i < 4; i++) af[i]  = *(const short8*)(pa + i * 512);
#pragma unroll
        for (int i = 0; i < 4; i++) bfr[i] = *(const short8*)(pb + i * 512);
#pragma unroll
        for (int i = 0; i < 4; i++)
#pragma unroll
            for (int j = 0; j < 4; j++)
                acc[i][j] = __builtin_amdgcn_mfma_f32_16x16x32_bf16(af[i], bfr[j], acc[i][j], 0, 0, 0);
        __syncthreads();
    }

    // epilogue: C/D layout col = lane&15, row = quad*4 + reg
    const int colBase = blockIdx.x * 128 + wc * 64 + m16;
    const int rowBase = blockIdx.y * 128 + wr * 64 + quad * 4;
#pragma unroll
    for (int i = 0; i < 4; i++) {
#pragma unroll
        for (int j = 0; j < 4; j++) {
            const int col = colBase + j * 16;
            const size_t rb = (size_t)(rowBase + i * 16);
#pragma unroll
            for (int r = 0; r < 4; r++)
                sim[(rb + r) * (size_t)Bn + col] = f2bf(acc[i][j][r]);
        }
    }
}

// ---------------- per-row loss: one block (256 thr) per row ------------------
__global__ __launch_bounds__(256) void row_loss(const unsigned short* __restrict__ sim,
                                                const int* __restrict__ labels,
                                                float* __restrict__ out, int Bn) {
    __shared__ float red[20];
    const int t = threadIdx.x;
    const int row = blockIdx.x;
    const int wave = t >> 6, lane = t & 63;

    const int mylab = labels[row];

    // 16 sims per thread, contiguous: j0 = t*16 (coalesced 32B/thread)
    const unsigned short* srow = sim + (size_t)row * Bn;
    float s[16];
    {
        const uint4* p = (const uint4*)srow + t * 2;
        uint4 v0 = p[0], v1 = p[1];
        unsigned w[8] = {v0.x, v0.y, v0.z, v0.w, v1.x, v1.y, v1.z, v1.w};
#pragma unroll
        for (int i = 0; i < 8; i++) {
            s[2 * i]     = __uint_as_float(w[i] << 16);
            s[2 * i + 1] = __uint_as_float(w[i] & 0xffff0000u);
        }
    }
    // labels for my 16 columns, straight from global (16KB array, L1/L2-hot)
    int lj[16];
    {
        const int4* lp = (const int4*)labels + t * 4;
        int4 a = lp[0], b = lp[1], c = lp[2], d = lp[3];
        lj[0]=a.x; lj[1]=a.y; lj[2]=a.z; lj[3]=a.w;
        lj[4]=b.x; lj[5]=b.y; lj[6]=b.z; lj[7]=b.w;
        lj[8]=c.x; lj[9]=c.y; lj[10]=c.z; lj[11]=c.w;
        lj[12]=d.x; lj[13]=d.y; lj[14]=d.z; lj[15]=d.w;
    }

    unsigned eqm = 0;
    float maxneg = -INFINITY, negsum = 0.f;
    int nneg = 0;
#pragma unroll
    for (int i = 0; i < 16; i++) {
        if (lj[i] == mylab) {
            eqm |= (1u << i);
        } else {
            nneg++;
            negsum += __expf(SCALE_NEG_C * s[i]);
            maxneg = fmaxf(maxneg, s[i]);
        }
    }

    // block max of maxneg
    float m = maxneg;
#pragma unroll
    for (int o = 32; o; o >>= 1) m = fmaxf(m, __shfl_down(m, o, 64));
    if (lane == 0) red[wave] = m;
    __syncthreads();
    maxneg = fmaxf(fmaxf(red[0], red[1]), fmaxf(red[2], red[3]));

    // phase 2: positive mask from stashed sims
    float possum = 0.f;
    int npos = 0;
#pragma unroll
    for (int i = 0; i < 16; i++) {
        if ((eqm >> i) & 1u) {
            float si = s[i];
            if (si < (1.0f - EPS_C) && (si - MARGIN_C) < maxneg) {
                npos++;
                possum += __expf(-SCALE_POS_C * si);
            }
        }
    }

    float a = negsum, b = possum, c = (float)nneg, d = (float)npos;
#pragma unroll
    for (int o = 32; o; o >>= 1) {
        a += __shfl_down(a, o, 64);
        b += __shfl_down(b, o, 64);
        c += __shfl_down(c, o, 64);
        d += __shfl_down(d, o, 64);
    }
    if (lane == 0) {
        red[4 + wave] = a; red[8 + wave] = b; red[12 + wave] = c; red[16 + wave] = d;
    }
    __syncthreads();
    if (t == 0) {
        float NS = red[4] + red[5] + red[6] + red[7];
        float PS = red[8] + red[9] + red[10] + red[11];
        float NN = red[12] + red[13] + red[14] + red[15];
        float NP = red[16] + red[17] + red[18] + red[19];
        if (NN >= 1.f && NP >= 1.f) {
            float pl = (1.f / SCALE_POS_C) * logf((PS + expf(-SCALE_POS_C * THRESH1_C)) / (NP + 1.f));
            float nl = (1.f / SCALE_NEG_C) * logf((NS + expf(SCALE_NEG_C * THRESH2_C)) / (NN + 1.f));
            float pr = logf(5.33f + expf(pl + nl));
            atomicAdd(out, pr / (float)Bn);
        }
    }
}

extern "C" void kernel_launch(void* const* d_in, const int* in_sizes, int n_in,
                              void* d_out, int out_size, void* d_ws, size_t ws_size,
                              hipStream_t stream) {
    const float* feats = (const float*)d_in[0];
    const int* labels  = (const int*)d_in[1];
    float* out = (float*)d_out;

    const int Bn = in_sizes[1];           // 4096
    const int Dn = in_sizes[0] / Bn;      // 1024

    unsigned short* fb  = (unsigned short*)d_ws;                 // bf16 feats [Bn][Dn]
    unsigned short* sim = fb + (size_t)Bn * Dn;                  // bf16 sim [Bn][Bn]

    const int n4 = (Bn * Dn) / 4;
    cvt_bf16<<<(n4 + 255) / 256, 256, 0, stream>>>(feats, fb, out, n4);

    dim3 g(Bn / 128, Bn / 128);
    gemm_sim<<<g, 256, 0, stream>>>(fb, sim, Bn, Dn);

    row_loss<<<Bn, 256, 0, stream>>>(sim, labels, out, Bn);
}

// Round 2
// 134.112 us; speedup vs baseline: 1.3236x; 1.3236x over previous
//
#include <hip/hip_runtime.h>
#include <hip/hip_bf16.h>
#include <math.h>

typedef __attribute__((ext_vector_type(8))) short short8;
typedef __attribute__((ext_vector_type(4))) float floatx4;

#define MARGIN_C   0.09f
#define SCALE_POS_C 2.0f
#define SCALE_NEG_C 40.0f
#define EPS_C      1e-5f
#define THRESH1_C  0.501f
#define THRESH2_C  0.531f

__device__ __forceinline__ unsigned short f2bf(float f) {
    unsigned u = __float_as_uint(f);
    u += 0x7fffu + ((u >> 16) & 1u);
    return (unsigned short)(u >> 16);
}

__device__ __forceinline__ void gld16(const void* g, void* l) {
    __builtin_amdgcn_global_load_lds(
        (const __attribute__((address_space(1))) void*)g,
        (__attribute__((address_space(3))) void*)l, 16, 0, 0);
}

// ---------------- fp32 -> bf16 conversion ------------------------------------
__global__ __launch_bounds__(256) void cvt_bf16(const float* __restrict__ in,
                                                unsigned short* __restrict__ out,
                                                int n4) {
    int i = blockIdx.x * 256 + threadIdx.x;
    if (i >= n4) return;
    float4 v = ((const float4*)in)[i];
    ushort4 o;
    o.x = f2bf(v.x); o.y = f2bf(v.y); o.z = f2bf(v.z); o.w = f2bf(v.w);
    ((ushort4*)out)[i] = o;
}

// ---------------- sim = F * F^T, symmetric: only tiles bx <= by --------------
// 128x128 tile, BK=32, 4 waves 2x2, each wave 64x64 via 4x4 MFMA 16x16x32.
// LDS k-chunk rotation: row r stores k-chunk (slot + r) & 3 at slot -> spreads
// fragment-read bank usage 2 banks -> 4 banks.
__global__ __launch_bounds__(256) void gemm_sim(const unsigned short* __restrict__ fb,
                                                unsigned short* __restrict__ sim,
                                                int Bn, int Dn) {
    __shared__ __align__(16) unsigned short As[4096]; // [128][32] row-major, k-rotated
    __shared__ __align__(16) unsigned short Bs[4096];

    // triangular tile decode: bid -> (by, bx), bx <= by
    const int bid = blockIdx.x;
    int by = (int)((sqrtf(8.f * (float)bid + 1.f) - 1.f) * 0.5f);
    while ((by + 1) * (by + 2) / 2 <= bid) by++;
    while (by * (by + 1) / 2 > bid) by--;
    const int bx = bid - by * (by + 1) / 2;

    const int t    = threadIdx.x;
    const int wave = t >> 6;
    const int lane = t & 63;
    const int wr   = wave >> 1, wc = wave & 1;
    const int quad = lane >> 4, m16 = lane & 15;

    // staging: thread t -> LDS offset t*8 shorts (row r0 = t>>2, slot = t&3).
    // rotation: fetch global k-chunk (slot + r0) & 3.
    const int slot = t & 3;
    const int r0   = t >> 2;
    const int kf   = (slot + r0) & 3;
    const unsigned short* gA0 = fb + (size_t)(by * 128 + r0) * Dn + kf * 8;
    const unsigned short* gB0 = fb + (size_t)(bx * 128 + r0) * Dn + kf * 8;
    const unsigned short* gA1 = gA0 + (size_t)64 * Dn;   // (r0+64)&3 == r0&3
    const unsigned short* gB1 = gB0 + (size_t)64 * Dn;
    unsigned short* lA0 = As + t * 8;
    unsigned short* lA1 = As + 2048 + t * 8;
    unsigned short* lB0 = Bs + t * 8;
    unsigned short* lB1 = Bs + 2048 + t * 8;

    floatx4 acc[4][4];
#pragma unroll
    for (int i = 0; i < 4; i++)
#pragma unroll
        for (int j = 0; j < 4; j++) acc[i][j] = (floatx4){0.f, 0.f, 0.f, 0.f};

    // fragment read: row = wr*64 + i*16 + m16 (row&3 == m16&3), want k-chunk quad
    // -> slot = (quad - m16) & 3
    const unsigned short* pa = As + (wr * 64 + m16) * 32 + ((quad - m16) & 3) * 8;
    const unsigned short* pb = Bs + (wc * 64 + m16) * 32 + ((quad - m16) & 3) * 8;

    for (int k0 = 0; k0 < Dn; k0 += 32) {
        gld16(gA0 + k0, lA0);
        gld16(gA1 + k0, lA1);
        gld16(gB0 + k0, lB0);
        gld16(gB1 + k0, lB1);
        __syncthreads();
        short8 af[4], bfr[4];
#pragma unroll
        for (int i = 0; i < 4; i++) af[i]  = *(const short8*)(pa + i * 512);
#pragma unroll
        for (int i = 0; i < 4; i++) bfr[i] = *(const short8*)(pb + i * 512);
#pragma unroll
        for (int i = 0; i < 4; i++)
#pragma unroll
            for (int j = 0; j < 4; j++)
                acc[i][j] = __builtin_amdgcn_mfma_f32_16x16x32_bf16(af[i], bfr[j], acc[i][j], 0, 0, 0);
        __syncthreads();
    }

    // epilogue: C/D layout col = lane&15, row = quad*4 + reg. Write (r,c) and
    // mirror (c,r) when off-diagonal.
    const int colBase = bx * 128 + wc * 64 + m16;
    const int rowBase = by * 128 + wr * 64 + quad * 4;
    const bool diag = (bx == by);
#pragma unroll
    for (int i = 0; i < 4; i++) {
#pragma unroll
        for (int j = 0; j < 4; j++) {
            const int col = colBase + j * 16;
            const int rb  = rowBase + i * 16;
#pragma unroll
            for (int r = 0; r < 4; r++) {
                const unsigned short v = f2bf(acc[i][j][r]);
                sim[(size_t)(rb + r) * Bn + col] = v;
                if (!diag) sim[(size_t)col * Bn + (rb + r)] = v;
            }
        }
    }
}

// ---------------- per-row loss: one block (256 thr) per row ------------------
__global__ __launch_bounds__(256) void row_loss(const unsigned short* __restrict__ sim,
                                                const int* __restrict__ labels,
                                                float* __restrict__ per_row, int Bn) {
    __shared__ float red[20];
    const int t = threadIdx.x;
    const int row = blockIdx.x;
    const int wave = t >> 6, lane = t & 63;

    const int mylab = labels[row];

    const unsigned short* srow = sim + (size_t)row * Bn;
    float s[16];
    {
        const uint4* p = (const uint4*)srow + t * 2;
        uint4 v0 = p[0], v1 = p[1];
        unsigned w[8] = {v0.x, v0.y, v0.z, v0.w, v1.x, v1.y, v1.z, v1.w};
#pragma unroll
        for (int i = 0; i < 8; i++) {
            s[2 * i]     = __uint_as_float(w[i] << 16);
            s[2 * i + 1] = __uint_as_float(w[i] & 0xffff0000u);
        }
    }
    int lj[16];
    {
        const int4* lp = (const int4*)labels + t * 4;
        int4 a = lp[0], b = lp[1], c = lp[2], d = lp[3];
        lj[0]=a.x; lj[1]=a.y; lj[2]=a.z; lj[3]=a.w;
        lj[4]=b.x; lj[5]=b.y; lj[6]=b.z; lj[7]=b.w;
        lj[8]=c.x; lj[9]=c.y; lj[10]=c.z; lj[11]=c.w;
        lj[12]=d.x; lj[13]=d.y; lj[14]=d.z; lj[15]=d.w;
    }

    unsigned eqm = 0;
    float maxneg = -INFINITY, negsum = 0.f;
    int nneg = 0;
#pragma unroll
    for (int i = 0; i < 16; i++) {
        if (lj[i] == mylab) {
            eqm |= (1u << i);
        } else {
            nneg++;
            negsum += __expf(SCALE_NEG_C * s[i]);
            maxneg = fmaxf(maxneg, s[i]);
        }
    }

    float m = maxneg;
#pragma unroll
    for (int o = 32; o; o >>= 1) m = fmaxf(m, __shfl_down(m, o, 64));
    if (lane == 0) red[wave] = m;
    __syncthreads();
    maxneg = fmaxf(fmaxf(red[0], red[1]), fmaxf(red[2], red[3]));

    float possum = 0.f;
    int npos = 0;
#pragma unroll
    for (int i = 0; i < 16; i++) {
        if ((eqm >> i) & 1u) {
            float si = s[i];
            if (si < (1.0f - EPS_C) && (si - MARGIN_C) < maxneg) {
                npos++;
                possum += __expf(-SCALE_POS_C * si);
            }
        }
    }

    float a = negsum, b = possum, c = (float)nneg, d = (float)npos;
#pragma unroll
    for (int o = 32; o; o >>= 1) {
        a += __shfl_down(a, o, 64);
        b += __shfl_down(b, o, 64);
        c += __shfl_down(c, o, 64);
        d += __shfl_down(d, o, 64);
    }
    if (lane == 0) {
        red[4 + wave] = a; red[8 + wave] = b; red[12 + wave] = c; red[16 + wave] = d;
    }
    __syncthreads();
    if (t == 0) {
        float NS = red[4] + red[5] + red[6] + red[7];
        float PS = red[8] + red[9] + red[10] + red[11];
        float NN = red[12] + red[13] + red[14] + red[15];
        float NP = red[16] + red[17] + red[18] + red[19];
        float pr = 0.0f;
        if (NN >= 1.f && NP >= 1.f) {
            float pl = (1.f / SCALE_POS_C) * logf((PS + expf(-SCALE_POS_C * THRESH1_C)) / (NP + 1.f));
            float nl = (1.f / SCALE_NEG_C) * logf((NS + expf(SCALE_NEG_C * THRESH2_C)) / (NN + 1.f));
            pr = logf(5.33f + expf(pl + nl));
        }
        per_row[row] = pr;
    }
}

// ---------------- final reduce: one block sums per_row -----------------------
__global__ __launch_bounds__(256) void reduce_loss(const float* __restrict__ per_row,
                                                   float* __restrict__ out, int Bn) {
    __shared__ float red[4];
    const int t = threadIdx.x;
    const int wave = t >> 6, lane = t & 63;
    float acc = 0.f;
    const float4* p = (const float4*)per_row;
    for (int i = t; i < Bn / 4; i += 256) {
        float4 v = p[i];
        acc += (v.x + v.y) + (v.z + v.w);
    }
#pragma unroll
    for (int o = 32; o; o >>= 1) acc += __shfl_down(acc, o, 64);
    if (lane == 0) red[wave] = acc;
    __syncthreads();
    if (t == 0) out[0] = (red[0] + red[1] + red[2] + red[3]) / (float)Bn;
}

extern "C" void kernel_launch(void* const* d_in, const int* in_sizes, int n_in,
                              void* d_out, int out_size, void* d_ws, size_t ws_size,
                              hipStream_t stream) {
    const float* feats = (const float*)d_in[0];
    const int* labels  = (const int*)d_in[1];
    float* out = (float*)d_out;

    const int Bn = in_sizes[1];           // 4096
    const int Dn = in_sizes[0] / Bn;      // 1024

    unsigned short* fb  = (unsigned short*)d_ws;                 // bf16 feats [Bn][Dn]
    unsigned short* sim = fb + (size_t)Bn * Dn;                  // bf16 sim [Bn][Bn]
    float* per_row = (float*)(sim + (size_t)Bn * Bn);            // [Bn]

    const int n4 = (Bn * Dn) / 4;
    cvt_bf16<<<(n4 + 255) / 256, 256, 0, stream>>>(feats, fb, n4);

    const int nt = Bn / 128;
    const int ntri = nt * (nt + 1) / 2;   // 528 for Bn=4096
    gemm_sim<<<ntri, 256, 0, stream>>>(fb, sim, Bn, Dn);

    row_loss<<<Bn, 256, 0, stream>>>(sim, labels, per_row, Bn);
    reduce_loss<<<1, 256, 0, stream>>>(per_row, out, Bn);
}